// Round 4
// baseline (816.135 us; speedup 1.0000x reference)
//
#include <hip/hip_runtime.h>

#define N 4096
#define N4 (N / 4)

// One cross-stencil pass, deferred 0.25 scaling:
// out[i][j] = in[i-1][j] + in[i+1][j] + in[i][j-1] + in[i][j+1]  (clamped)
__global__ __launch_bounds__(256) void stencil_pass(const float* __restrict__ in,
                                                    float* __restrict__ out) {
    const int j4 = blockIdx.x * blockDim.x + threadIdx.x;  // float4 column index
    const int i  = blockIdx.y * blockDim.y + threadIdx.y;  // row
    const int j  = j4 * 4;

    const float4* in4 = (const float4*)in;
    const int rowBase = i * N4;

    float4 c = in4[rowBase + j4];

    const int iu = (i == 0)     ? 0     : i - 1;
    const int id = (i == N - 1) ? N - 1 : i + 1;
    float4 u = in4[iu * N4 + j4];
    float4 d = in4[id * N4 + j4];

    float l = (j == 0)      ? c.x : in[i * N + j - 1];
    float r = (j + 4 >= N)  ? c.w : in[i * N + j + 4];

    float4 o;
    o.x = (u.x + d.x) + (l   + c.y);
    o.y = (u.y + d.y) + (c.x + c.z);
    o.z = (u.z + d.z) + (c.y + c.w);
    o.w = (u.w + d.w) + (c.z + r);

    ((float4*)out)[rowBase + j4] = o;
}

// Epilogue: rescale rx by 2^-64, AO, diffuse from normals, modulate.
__global__ __launch_bounds__(256) void epilogue_k(const float* __restrict__ rx,
                                                  const float* __restrict__ x,
                                                  const float* __restrict__ nrm,
                                                  float* __restrict__ out) {
    const int idx = blockIdx.x * blockDim.x + threadIdx.x;  // float4 index
    if (idx >= N * N / 4) return;

    const float4 r  = ((const float4*)rx)[idx];
    const float4 h  = ((const float4*)x)[idx];
    const float4 n0 = ((const float4*)(nrm))[idx];
    const float4 n1 = ((const float4*)(nrm + (size_t)N * N))[idx];
    const float4 n2 = ((const float4*)(nrm + 2 * (size_t)N * N))[idx];

    const float SC = 0x1p-64f;   // undo 32 deferred 0.25 factors
    const float L0 = 0.7053f, L1 = -0.7053f, L2 = 0.7053f;

    float4 o;
    {
        float ao = 1.0f - fminf(fmaxf((r.x * SC - h.x) * 4.0f, 0.0f), 1.0f);
        float d1 = fmaxf(n0.x * L0 + n1.x * L1 + n2.x * L2, 0.0f);
        o.x = (d1 * 0.3f + 0.7f) * ao;
    }
    {
        float ao = 1.0f - fminf(fmaxf((r.y * SC - h.y) * 4.0f, 0.0f), 1.0f);
        float d1 = fmaxf(n0.y * L0 + n1.y * L1 + n2.y * L2, 0.0f);
        o.y = (d1 * 0.3f + 0.7f) * ao;
    }
    {
        float ao = 1.0f - fminf(fmaxf((r.z * SC - h.z) * 4.0f, 0.0f), 1.0f);
        float d1 = fmaxf(n0.z * L0 + n1.z * L1 + n2.z * L2, 0.0f);
        o.z = (d1 * 0.3f + 0.7f) * ao;
    }
    {
        float ao = 1.0f - fminf(fmaxf((r.w * SC - h.w) * 4.0f, 0.0f), 1.0f);
        float d1 = fmaxf(n0.w * L0 + n1.w * L1 + n2.w * L2, 0.0f);
        o.w = (d1 * 0.3f + 0.7f) * ao;
    }
    ((float4*)out)[idx] = o;
}

extern "C" void kernel_launch(void* const* d_in, const int* in_sizes, int n_in,
                              void* d_out, int out_size, void* d_ws, size_t ws_size,
                              hipStream_t stream) {
    const float* x       = (const float*)d_in[0];
    const float* normals = (const float*)d_in[1];
    float* out = (float*)d_out;
    float* ws  = (float*)d_ws;

    dim3 sblock(64, 4);
    dim3 sgrid(N / (64 * 4), N / 4);

    // Pass 1: x -> ws
    stencil_pass<<<sgrid, sblock, 0, stream>>>(x, ws);

    // Passes 2..32: ping-pong ws <-> out. Pass t result: odd->ws, even->out.
    const float* src = ws;
    float*       dst = out;
    for (int t = 2; t <= 32; ++t) {
        stencil_pass<<<sgrid, sblock, 0, stream>>>(src, dst);
        const float* nsrc = dst;
        dst = (float*)src;
        src = nsrc;
    }
    // After pass 32 (even), rx lives in d_out. Epilogue reads it and rewrites
    // d_out in place (pure elementwise, same-index read-then-write: safe).

    const int nv4 = N * N / 4;
    dim3 eblock(256);
    dim3 egrid((nv4 + 255) / 256);
    epilogue_k<<<egrid, eblock, 0, stream>>>(out, x, normals, out);
}

// Round 5
// 344.172 us; speedup vs baseline: 2.3713x; 2.3713x over previous
//
#include <hip/hip_runtime.h>

#define N 4096
#define TILE 64
#define HALO 8
#define SDIM 80            // TILE + 2*HALO
#define S4   (SDIM / 4)    // 20 float4 per staging row
#define LSTRIDE 80         // LDS row stride in words
#define NSTEPS 8           // stencil iterations fused per pass
#define GH 7               // rows per thread in the update loop

// 8 fused cross-stencil iterations (deferred 0.25 scaling -> pure adds).
// Staging tile 80x80 in LDS, ping-pong between two buffers. After 8 steps
// the interior 64x64 (staging [8,72)^2) is exact: edge garbage propagates
// 1 cell/step and reaches at most rows/cols 7 / 72 after the last step.
// Global edge replication = per-element clamp selects (only fires at the
// true image boundary, matching ReplicationPad2d(1) applied every step).
template <int FUSE>
__global__ __launch_bounds__(256) void stencil8(const float* __restrict__ src,
                                                float* __restrict__ dst,
                                                const float* __restrict__ xin,
                                                const float* __restrict__ nrm) {
    __shared__ float lds[2][SDIM * LSTRIDE];
    const int bx = blockIdx.x, by = blockIdx.y;
    const int gi0 = by * TILE - HALO;
    const int gj0 = bx * TILE - HALO;
    const int tid = threadIdx.x;

    // ---- stage 80x80 (clamped) into lds[0] ----
    for (int idx = tid; idx < SDIM * S4; idx += 256) {
        const int r  = idx / S4;
        const int j4 = idx - r * S4;
        int gr = gi0 + r;
        gr = gr < 0 ? 0 : (gr > N - 1 ? N - 1 : gr);
        const int gj = gj0 + 4 * j4;
        float4 v;
        if (gj >= 0 && gj + 3 <= N - 1) {
            v = *(const float4*)(src + (size_t)gr * N + gj);
        } else {
            const float* row = src + (size_t)gr * N;
            const int c0 = min(max(gj + 0, 0), N - 1);
            const int c1 = min(max(gj + 1, 0), N - 1);
            const int c2 = min(max(gj + 2, 0), N - 1);
            const int c3 = min(max(gj + 3, 0), N - 1);
            v = make_float4(row[c0], row[c1], row[c2], row[c3]);
        }
        *(float4*)&lds[0][r * LSTRIDE + 4 * j4] = v;
    }
    __syncthreads();

    // ---- update-loop thread mapping: 7-row column strips ----
    const int g   = tid / S4;          // row group
    const int j4v = tid - g * S4;      // float4 column 0..19
    const int r0  = 1 + g * GH;
    const int j   = 4 * j4v;
    const int gjx = gj0 + j;
    const bool lcl    = (gjx == 0);         // global left edge at lane .x
    const bool rcl    = (gjx + 3 == N - 1); // global right edge at lane .w
    const bool active = (r0 <= SDIM - 2);   // g < 12

    for (int p = 0; p < NSTEPS; ++p) {
        const float* __restrict__ A = lds[p & 1];
        float* __restrict__ B = lds[(p & 1) ^ 1];
        if (active) {
            float4 prev = *(const float4*)&A[(r0 - 1) * LSTRIDE + j];
            float4 cur  = *(const float4*)&A[(r0)*LSTRIDE + j];
#pragma unroll
            for (int i = 0; i < GH; ++i) {
                const int r = r0 + i;
                if (r > SDIM - 2) break;   // rows 1..78
                const float4 next = *(const float4*)&A[(r + 1) * LSTRIDE + j];
                const int gr = gi0 + r;
                const float4 up = (gr == 0)     ? cur : prev;
                const float4 dn = (gr == N - 1) ? cur : next;
                const float lft = lcl ? cur.x : A[r * LSTRIDE + j - 1];
                const float rgt = rcl ? cur.w : A[r * LSTRIDE + j + 4];
                float4 o;
                o.x = (up.x + dn.x) + (lft   + cur.y);
                o.y = (up.y + dn.y) + (cur.x + cur.z);
                o.z = (up.z + dn.z) + (cur.y + cur.w);
                o.w = (up.w + dn.w) + (cur.z + rgt);
                *(float4*)&B[r * LSTRIDE + j] = o;
                prev = cur;
                cur = next;
            }
        }
        __syncthreads();
    }

    // ---- store interior 64x64 (result in lds[0]; NSTEPS even) ----
    const float SC = 0x1p-64f;  // undo 32 deferred 0.25 factors (applied once)
    const float L0 = 0.7053f, L1 = -0.7053f, L2 = 0.7053f;
    for (int idx = tid; idx < TILE * TILE / 4; idx += 256) {
        const int rr  = idx >> 4;
        const int jj4 = idx & 15;
        const size_t base = (size_t)(by * TILE + rr) * N + bx * TILE + 4 * jj4;
        const float4 v = *(const float4*)&lds[0][(HALO + rr) * LSTRIDE + HALO + 4 * jj4];
        if (FUSE) {
            const float4 h  = *(const float4*)(xin + base);
            const float4 n0 = *(const float4*)(nrm + base);
            const float4 n1 = *(const float4*)(nrm + (size_t)N * N + base);
            const float4 n2 = *(const float4*)(nrm + 2 * (size_t)N * N + base);
            float4 o;
            {
                float ao = 1.0f - fminf(fmaxf((v.x * SC - h.x) * 4.0f, 0.0f), 1.0f);
                float d1 = fmaxf(n0.x * L0 + n1.x * L1 + n2.x * L2, 0.0f);
                o.x = (d1 * 0.3f + 0.7f) * ao;
            }
            {
                float ao = 1.0f - fminf(fmaxf((v.y * SC - h.y) * 4.0f, 0.0f), 1.0f);
                float d1 = fmaxf(n0.y * L0 + n1.y * L1 + n2.y * L2, 0.0f);
                o.y = (d1 * 0.3f + 0.7f) * ao;
            }
            {
                float ao = 1.0f - fminf(fmaxf((v.z * SC - h.z) * 4.0f, 0.0f), 1.0f);
                float d1 = fmaxf(n0.z * L0 + n1.z * L1 + n2.z * L2, 0.0f);
                o.z = (d1 * 0.3f + 0.7f) * ao;
            }
            {
                float ao = 1.0f - fminf(fmaxf((v.w * SC - h.w) * 4.0f, 0.0f), 1.0f);
                float d1 = fmaxf(n0.w * L0 + n1.w * L1 + n2.w * L2, 0.0f);
                o.w = (d1 * 0.3f + 0.7f) * ao;
            }
            *(float4*)(dst + base) = o;
        } else {
            *(float4*)(dst + base) = v;
        }
    }
}

extern "C" void kernel_launch(void* const* d_in, const int* in_sizes, int n_in,
                              void* d_out, int out_size, void* d_ws, size_t ws_size,
                              hipStream_t stream) {
    const float* x       = (const float*)d_in[0];
    const float* normals = (const float*)d_in[1];
    float* out = (float*)d_out;
    float* ws  = (float*)d_ws;

    dim3 grid(N / TILE, N / TILE);
    dim3 block(256);

    // 32 iterations = 4 passes x 8 fused steps
    stencil8<0><<<grid, block, 0, stream>>>(x,   ws,  nullptr, nullptr);
    stencil8<0><<<grid, block, 0, stream>>>(ws,  out, nullptr, nullptr);
    stencil8<0><<<grid, block, 0, stream>>>(out, ws,  nullptr, nullptr);
    // final pass: 8 steps + fused AO/diffuse epilogue
    stencil8<1><<<grid, block, 0, stream>>>(ws,  out, x, normals);
}